// Round 1
// baseline (246.123 us; speedup 1.0000x reference)
//
#include <hip/hip_runtime.h>
#include <cstdint>
#include <cstddef>

// Problem constants
constexpr int N = 4096;
constexpr int B = 32;
constexpr int BN = B * N;          // 131072
constexpr size_t NN = (size_t)N * N;  // 16777216

constexpr float ALPHA = 0.025f;
constexpr float BETA = 0.00025f;
constexpr float T_NOW = 10.0f;
constexpr float INV_EXP_TAU = 0.02f;          // 1/50
constexpr float INV_TAU_V = 0.98019867f;      // exp(-1/50)
constexpr float INV_TAU_I = 0.36787944f;      // exp(-1)

// ---------------------------------------------------------------------------
// Pass A: per-neuron spike masks + max_st + rowfac; writes S output.
// ---------------------------------------------------------------------------
__global__ __launch_bounds__(256) void pass_a(
    const float* __restrict__ mem_pot, const float* __restrict__ mem_pot_p,
    const float* __restrict__ st, float* __restrict__ S_out,
    uint32_t* __restrict__ maskS, uint32_t* __restrict__ maskSP,
    float* __restrict__ max_st, float* __restrict__ rowfac) {
  int j = blockIdx.x * blockDim.x + threadIdx.x;
  if (j >= N) return;
  float stj = st[j];
  uint32_t ms = 0u, msp = 0u;
  float maxv = -3.0e38f;
  #pragma unroll
  for (int b = 0; b < B; ++b) {
    float p = mem_pot[b * N + j];
    float pp = mem_pot_p[b * N + j];
    // S = clip(ceil(p - 1), 0, 1)  ==  (p - 1) > 0
    bool s = (p - 1.0f) > 0.0f;
    bool sp = ((pp - 1.0f) - ALPHA) > 0.0f;
    S_out[b * N + j] = s ? 1.0f : 0.0f;
    ms |= (uint32_t)s << b;
    msp |= (uint32_t)sp << b;
    maxv = fmaxf(maxv, s ? T_NOW : stj);
  }
  maskS[j] = ms;
  maskSP[j] = msp;
  max_st[j] = maxv;
  rowfac[j] = msp ? ALPHA : 0.0f;  // sp_max[j] > 0 ? ALPHA : 0
}

// ---------------------------------------------------------------------------
// Pass B: one block per row i. Compute W_new[i,:], write it, and accumulate
// SWT[b,i] = sum_j S[b,j] * W_new[i,j]  (this is (S @ W_new^T)[b,i]).
// SWT staged into the mem_pot_paired output region.
// ---------------------------------------------------------------------------
__global__ __launch_bounds__(256) void pass_b(
    const float* __restrict__ W, const uint32_t* __restrict__ maskS,
    const float* __restrict__ max_st, const float* __restrict__ rowfac,
    float* __restrict__ Wout, float* __restrict__ SWT) {
  int i = blockIdx.x;
  int tid = threadIdx.x;
  float mst_i = max_st[i];
  float fac_i = rowfac[i];

  const float4* __restrict__ Wrow = (const float4*)(W + (size_t)i * N);
  float4* __restrict__ Wo = (float4*)(Wout + (size_t)i * N);
  const float4* __restrict__ mstv = (const float4*)max_st;
  const uint4* __restrict__ mv = (const uint4*)maskS;

  float acc[32];
  #pragma unroll
  for (int b = 0; b < 32; ++b) acc[b] = 0.0f;

  auto upd = [&](float w, float mstj) -> float {
    float d = fabsf(mst_i - mstj);
    float ex = __expf(d * INV_EXP_TAU);
    float u = w + BETA - fac_i * ex;
    u = fminf(fmaxf(u, 0.0f), 1.0f);
    return (w > 0.0f) ? u : w;
  };

  #pragma unroll
  for (int it = 0; it < 4; ++it) {
    int idx = it * 256 + tid;  // float4 index within row
    float4 w = Wrow[idx];
    float4 mj = mstv[idx];
    uint4 m = mv[idx];
    float4 wo;
    wo.x = upd(w.x, mj.x);
    wo.y = upd(w.y, mj.y);
    wo.z = upd(w.z, mj.z);
    wo.w = upd(w.w, mj.w);
    Wo[idx] = wo;
    #pragma unroll
    for (int b = 0; b < 32; ++b) {
      acc[b] = fmaf(wo.x, (float)((m.x >> b) & 1u), acc[b]);
      acc[b] = fmaf(wo.y, (float)((m.y >> b) & 1u), acc[b]);
      acc[b] = fmaf(wo.z, (float)((m.z >> b) & 1u), acc[b]);
      acc[b] = fmaf(wo.w, (float)((m.w >> b) & 1u), acc[b]);
    }
  }

  // Block reduction of acc[0..31] over 256 threads.
  int lane = tid & 63;
  int wid = tid >> 6;
  __shared__ float red[4][32];
  #pragma unroll
  for (int b = 0; b < 32; ++b) {
    float v = acc[b];
    #pragma unroll
    for (int off = 32; off >= 1; off >>= 1) v += __shfl_xor(v, off, 64);
    acc[b] = v;
  }
  if (lane == 0) {
    #pragma unroll
    for (int b = 0; b < 32; ++b) red[wid][b] = acc[b];
  }
  __syncthreads();
  if (tid < 32) {
    float s = red[0][tid] + red[1][tid] + red[2][tid] + red[3][tid];
    SWT[tid * N + i] = s;
  }
}

// ---------------------------------------------------------------------------
// Pass C: column sweep. SW[b,j] = sum_k S[b,k] * W_new[k,j].
// Grid: (col tiles of 256) x (row strips of 128). Atomic partials into the
// zero-initialized mem_cur output region.
// ---------------------------------------------------------------------------
__global__ __launch_bounds__(256) void pass_c(
    const float* __restrict__ Wn, const uint32_t* __restrict__ maskS,
    float* __restrict__ SW) {
  int j = blockIdx.x * 256 + threadIdx.x;
  int k0 = blockIdx.y * 128;
  float acc[32];
  #pragma unroll
  for (int b = 0; b < 32; ++b) acc[b] = 0.0f;
  for (int kk = 0; kk < 128; ++kk) {
    int k = k0 + kk;
    float w = Wn[(size_t)k * N + j];
    uint32_t m = maskS[k];  // block-uniform -> scalar load
    #pragma unroll
    for (int b = 0; b < 32; ++b) {
      acc[b] += (m & (1u << b)) ? w : 0.0f;
    }
  }
  #pragma unroll
  for (int b = 0; b < 32; ++b) atomicAdd(&SW[b * N + j], acc[b]);
}

// ---------------------------------------------------------------------------
// Pass D: integrate + leak + reset + refractory. Reads SW (mem_cur region)
// and SWT (mem_pot_paired region) staged by passes C/B, overwrites in place.
// ---------------------------------------------------------------------------
__global__ __launch_bounds__(256) void pass_d(
    const float* __restrict__ inp, const float* __restrict__ mem_pot,
    const float* __restrict__ mem_cur, const float* __restrict__ mem_pot_p,
    const float* __restrict__ mem_cur_p, const int* __restrict__ refrac_in,
    const uint32_t* __restrict__ maskS, const uint32_t* __restrict__ maskSP,
    float* __restrict__ pot_out, float* __restrict__ cur_out,
    float* __restrict__ potp_out, float* __restrict__ curp_out,
    float* __restrict__ refrac_out) {
  int e = blockIdx.x * 256 + threadIdx.x;  // e < B*N
  int b = e >> 12;   // / N
  int j = e & (N - 1);
  int r = refrac_in[e];
  int rd = (r > 0) ? (r - 1) : r;
  bool active = (rd == 0);
  bool s = (maskS[j] >> b) & 1u;
  bool sp = (maskSP[j] >> b) & 1u;
  float SW = cur_out[e];    // staged by pass C
  float SWT = potp_out[e];  // staged by pass B
  float cur = mem_cur[e], pot = mem_pot[e];
  float curp = mem_cur_p[e], potp = mem_pot_p[e];

  float cur_n = active ? (inp[e] + SW + cur) : cur;
  float curp_n = active ? (SWT + curp) : curp;
  float pot_n = active ? (cur_n + pot) : pot;
  float potp_n = active ? (curp_n + potp) : potp;

  pot_n *= INV_TAU_V;
  cur_n *= INV_TAU_I;
  potp_n *= INV_TAU_V;
  curp_n *= INV_TAU_I;

  if (s) pot_n = 0.0f;
  if (sp) potp_n = 0.0f;
  int rn = s ? 2 : rd;

  pot_out[e] = pot_n;
  cur_out[e] = cur_n;
  potp_out[e] = potp_n;
  curp_out[e] = curp_n;
  refrac_out[e] = (float)rn;
}

// ---------------------------------------------------------------------------
extern "C" void kernel_launch(void* const* d_in, const int* in_sizes, int n_in,
                              void* d_out, int out_size, void* d_ws, size_t ws_size,
                              hipStream_t stream) {
  const float* inp = (const float*)d_in[0];
  const float* W = (const float*)d_in[1];
  const float* mem_pot = (const float*)d_in[2];
  const float* mem_cur = (const float*)d_in[3];
  const float* mem_pot_p = (const float*)d_in[4];
  const float* mem_cur_p = (const float*)d_in[5];
  const float* st = (const float*)d_in[6];
  const int* refrac = (const int*)d_in[7];

  float* out = (float*)d_out;
  // Output order: S(BN), mem_pot(BN), W_new(NN), mem_cur(BN),
  //               mem_pot_p(BN), mem_cur_p(BN), refrac(BN)
  float* S_out = out;
  float* pot_out = out + BN;
  float* W_out = out + 2 * (size_t)BN;
  float* cur_out = W_out + NN;
  float* potp_out = cur_out + BN;
  float* curp_out = potp_out + BN;
  float* refrac_out = curp_out + BN;

  uint32_t* maskS = (uint32_t*)d_ws;
  uint32_t* maskSP = maskS + N;
  float* max_st = (float*)(maskSP + N);
  float* rowfac = max_st + N;

  // Zero the SW accumulator region (mem_cur output) for pass C atomics.
  hipMemsetAsync(cur_out, 0, (size_t)BN * sizeof(float), stream);

  pass_a<<<N / 256, 256, 0, stream>>>(mem_pot, mem_pot_p, st, S_out, maskS,
                                      maskSP, max_st, rowfac);
  pass_b<<<N, 256, 0, stream>>>(W, maskS, max_st, rowfac, W_out, potp_out);
  pass_c<<<dim3(N / 256, N / 128), 256, 0, stream>>>(W_out, maskS, cur_out);
  pass_d<<<BN / 256, 256, 0, stream>>>(inp, mem_pot, mem_cur, mem_pot_p,
                                       mem_cur_p, refrac, maskS, maskSP,
                                       pot_out, cur_out, potp_out, curp_out,
                                       refrac_out);
}